// Round 2
// baseline (334.218 us; speedup 1.0000x reference)
//
#include <hip/hip_runtime.h>

typedef float2 cplx;

constexpr int SS   = 64;
constexpr int NC   = 16;
constexpr int NB   = 4;
constexpr int NM1  = 4;
constexpr int NM2  = 5;
constexpr int NPIX = SS * SS;           // 4096
constexpr float TWO_PI = 6.28318530717958647692f;

__device__ inline void cmac(float& ax, float& ay, cplx a, cplx b) {
    ax += a.x * b.x - a.y * b.y;
    ay += a.x * b.y + a.y * b.x;
}

// ---------------- K1: h = fc0(x,gx,gy); hn = instance_norm(h) -----------------
__global__ __launch_bounds__(256) void k_h_inorm(
    const float* __restrict__ x, const float* __restrict__ fc0_w,
    const float* __restrict__ fc0_b, float* __restrict__ h, float* __restrict__ hn)
{
    int bc = blockIdx.x;                 // b*16+c
    int b = bc >> 4, c = bc & 15;
    int tid = threadIdx.x;
    float w0 = fc0_w[c * 3 + 0], w1 = fc0_w[c * 3 + 1], w2 = fc0_w[c * 3 + 2];
    float bb = fc0_b[c];
    const float inv63 = 1.0f / 63.0f;
    float vals[16];
    float s = 0.f;
    for (int t = 0; t < 16; ++t) {
        int pix = t * 256 + tid;
        int z = pix >> 6, xx = pix & 63;
        float xv = x[b * NPIX + pix];
        float v = w0 * xv + w1 * (z * inv63) + w2 * (xx * inv63) + bb;
        vals[t] = v; s += v;
    }
    __shared__ float rs[256];
    rs[tid] = s; __syncthreads();
    for (int off = 128; off > 0; off >>= 1) {
        if (tid < off) rs[tid] += rs[tid + off];
        __syncthreads();
    }
    float mean = rs[0] * (1.0f / NPIX);
    __syncthreads();
    float s2 = 0.f;
    for (int t = 0; t < 16; ++t) { float d = vals[t] - mean; s2 += d * d; }
    rs[tid] = s2; __syncthreads();
    for (int off = 128; off > 0; off >>= 1) {
        if (tid < off) rs[tid] += rs[tid + off];
        __syncthreads();
    }
    float rstd = rsqrtf(rs[0] * (1.0f / NPIX) + 1e-5f);
    for (int t = 0; t < 16; ++t) {
        int pix = t * 256 + tid;
        h[bc * NPIX + pix]  = vals[t];
        hn[bc * NPIX + pix] = (vals[t] - mean) * rstd;
    }
}

// ---------------- K2: alpha = fft2(hn), per (b,c) fused 2-stage DFT -----------
__global__ __launch_bounds__(256) void k_fft2(
    const float* __restrict__ hn, cplx* __restrict__ alpha)
{
    __shared__ float tile[64 * 64];
    __shared__ cplx  T1[64 * 64];
    __shared__ cplx  W[64];
    int bc = blockIdx.x, tid = threadIdx.x;
    if (tid < 64) {
        float sn, cs;
        sincosf(-TWO_PI * (float)tid / 64.0f, &sn, &cs);
        W[tid] = make_float2(cs, sn);
    }
    for (int t = 0; t < 16; ++t) { int e = t * 256 + tid; tile[e] = hn[bc * NPIX + e]; }
    __syncthreads();
    // stage 1: DFT over rows (Sx): T1[p][j] = sum_i tile[i][j] * W[(p*i)&63]
    for (int t = 0; t < 16; ++t) {
        int e = t * 256 + tid; int p = e >> 6, j = e & 63;
        float ax = 0.f, ay = 0.f;
        for (int i = 0; i < 64; ++i) {
            float v = tile[i * 64 + j];
            cplx w = W[(p * i) & 63];
            ax += v * w.x; ay += v * w.y;
        }
        T1[e] = make_float2(ax, ay);
    }
    __syncthreads();
    // stage 2: DFT over cols (Sy): alpha[p][q] = sum_j T1[p][j] * W[(q*j)&63]
    for (int t = 0; t < 16; ++t) {
        int e = t * 256 + tid; int p = e >> 6, q = e & 63;
        float ax = 0.f, ay = 0.f;
        for (int j = 0; j < 64; ++j) cmac(ax, ay, T1[p * 64 + j], W[(q * j) & 63]);
        alpha[bc * NPIX + e] = make_float2(ax, ay);
    }
}

// ---------------- K3: pole reciprocals A, B (+ transposed B) -----------------
__global__ __launch_bounds__(256) void k_poles(
    const float* __restrict__ p1r, const float* __restrict__ p1i,
    const float* __restrict__ p2r, const float* __restrict__ p2i,
    const float* __restrict__ t_grid, const float* __restrict__ x_grid,
    cplx* __restrict__ A, cplx* __restrict__ Bq, cplx* __restrict__ BqT)
{
    int idx = blockIdx.x * 256 + threadIdx.x;
    float dty = x_grid[1] - x_grid[0];
    float dtx = t_grid[1] - t_grid[0];
    const int NA = 64 * NC * NC * NM1;       // 65536
    const int NBQ = 64 * NC * NC * NM2;      // 81920
    if (idx < NA) {
        // A[o][i][k][p] = 1 / (i*om1[o] - p1[i,k,p])
        int p = idx & 3, k = (idx >> 2) & 15, i = (idx >> 6) & 15, o = idx >> 10;
        int kf = (o < 32) ? o : o - 64;
        float om = TWO_PI * (float)kf / (64.0f * dty);
        float dr = -p1r[(i * 16 + k) * 4 + p];
        float di = om - p1i[(i * 16 + k) * 4 + p];
        float inv = 1.0f / (dr * dr + di * di);
        A[idx] = make_float2(dr * inv, -di * inv);
    } else {
        int j = idx - NA;
        if (j < NBQ) {
            // Bq[x][i][k][q] = 1 / (i*om2[x] - p2[i,k,q])
            int q = j % 5, k = (j / 5) & 15, i = (j / 80) & 15, xx = j / 1280;
            int kf = (xx < 32) ? xx : xx - 64;
            float om = TWO_PI * (float)kf / (64.0f * dtx);
            float dr = -p2r[(i * 16 + k) * 5 + q];
            float di = om - p2i[(i * 16 + k) * 5 + q];
            float inv = 1.0f / (dr * dr + di * di);
            cplx v = make_float2(dr * inv, -di * inv);
            Bq[j] = v;
            BqT[((i * 16 + k) * 5 + q) * 64 + xx] = v;
        }
    }
}

// ---------------- K4: G[o][x][k][i] = sum_{p,q} res[i,k,p,q]*A[o,i,k,p]*B[x,i,k,q]
__global__ __launch_bounds__(256) void k_G(
    const float* __restrict__ resr, const float* __restrict__ resi,
    const cplx* __restrict__ A, const cplx* __restrict__ Bq, cplx* __restrict__ G)
{
    int o = blockIdx.x;
    int t = threadIdx.x;                 // t = k*16 + i  (coalesced G writes)
    int k = t >> 4, i = t & 15;
    cplx a[NM1];
    for (int p = 0; p < NM1; ++p) a[p] = A[((o * 16 + i) * 16 + k) * 4 + p];
    int rbase = (i * 16 + k) * NM1 * NM2;
    cplx Cq[NM2];
    for (int q = 0; q < NM2; ++q) {
        float cx = 0.f, cy = 0.f;
        for (int p = 0; p < NM1; ++p) {
            float rr = resr[rbase + p * NM2 + q], ri = resi[rbase + p * NM2 + q];
            cx += rr * a[p].x - ri * a[p].y;
            cy += rr * a[p].y + ri * a[p].x;
        }
        Cq[q] = make_float2(cx, cy);
    }
    for (int xx = 0; xx < 64; ++xx) {
        float gx = 0.f, gy = 0.f;
        int bbase = ((xx * 16 + i) * 16 + k) * NM2;
        for (int q = 0; q < NM2; ++q) cmac(gx, gy, Cq[q], Bq[bbase + q]);
        G[(o * 64 + xx) * 256 + t] = make_float2(gx, gy);
    }
}

// ---------------- K5: r1[b][k][o][x] = sum_i alpha[b][i][o][x]*G[o][x][i][k] --
__global__ __launch_bounds__(64) void k_r1(
    const cplx* __restrict__ alpha, const cplx* __restrict__ G, cplx* __restrict__ r1)
{
    int ox = blockIdx.x;                 // o*64+x
    int t = threadIdx.x;                 // 64 threads = (b,k) and loader (b,i)
    __shared__ cplx as[64];              // alpha[b][i] at this (o,x)
    as[t] = alpha[t * NPIX + ox];
    __syncthreads();
    int b = t >> 4, k = t & 15;
    const cplx* g = &G[ox * 256 + k * 16];
    const cplx* av = &as[b * 16];
    float ax = 0.f, ay = 0.f;
    for (int i = 0; i < 16; ++i) cmac(ax, ay, av[i], g[i]);
    r1[t * NPIX + ox] = make_float2(ax, ay);
}

// ---------------- K6: r2[b][k][p][q] (block per (b,i,k), butterfly + atomics) -
__global__ __launch_bounds__(64) void k_r2(
    const cplx* __restrict__ alpha, const cplx* __restrict__ A,
    const cplx* __restrict__ BqT, const float* __restrict__ resr,
    const float* __restrict__ resi, cplx* __restrict__ r2)
{
    int blk = blockIdx.x;                // (b*16+i)*16+k
    int k = blk & 15, i = (blk >> 4) & 15, b = blk >> 8;
    int o = threadIdx.x;                 // lane = frequency o
    __shared__ cplx as[64 * 65];         // padded: [o][x] at stride 65
    const cplx* abase = &alpha[(b * 16 + i) * NPIX];
    for (int it = 0; it < 64; ++it) as[it * 65 + o] = abase[it * 64 + o];
    __syncthreads();
    // inner[q] = sum_x alpha[b,i,o,x] * B[x,i,k,q]
    float inx[NM2], iny[NM2];
    for (int q = 0; q < NM2; ++q) { inx[q] = 0.f; iny[q] = 0.f; }
    const cplx* bq = &BqT[(i * 16 + k) * NM2 * 64];
    for (int xx = 0; xx < 64; ++xx) {
        cplx av = as[o * 65 + xx];
        for (int q = 0; q < NM2; ++q) {
            cplx bv = bq[q * 64 + xx];
            inx[q] += av.x * bv.x - av.y * bv.y;
            iny[q] += av.x * bv.y + av.y * bv.x;
        }
    }
    float px[NM1][NM2], py[NM1][NM2];
    for (int p = 0; p < NM1; ++p) {
        cplx a = A[((o * 16 + i) * 16 + k) * 4 + p];
        for (int q = 0; q < NM2; ++q) {
            px[p][q] = a.x * inx[q] - a.y * iny[q];
            py[p][q] = a.x * iny[q] + a.y * inx[q];
        }
    }
    for (int m = 32; m > 0; m >>= 1) {
        for (int p = 0; p < NM1; ++p)
            for (int q = 0; q < NM2; ++q) {
                px[p][q] += __shfl_xor(px[p][q], m, 64);
                py[p][q] += __shfl_xor(py[p][q], m, 64);
            }
    }
    if (o == 0) {
        int rbase = (i * 16 + k) * NM1 * NM2;
        for (int p = 0; p < NM1; ++p)
            for (int q = 0; q < NM2; ++q) {
                float rr = resr[rbase + p * NM2 + q], ri = resi[rbase + p * NM2 + q];
                float vx = rr * px[p][q] - ri * py[p][q];
                float vy = rr * py[p][q] + ri * px[p][q];
                cplx* dst = &r2[((b * 16 + k) * NM1 + p) * NM2 + q];
                atomicAdd(&dst->x, vx);
                atomicAdd(&dst->y, vy);
            }
    }
}

// ---------------- K7: x1 = Re(ifft2(r1)) per (b,k) ----------------------------
__global__ __launch_bounds__(256) void k_ifft2(
    const cplx* __restrict__ r1, float* __restrict__ x1)
{
    extern __shared__ float smem[];
    cplx* tile = (cplx*)smem;            // 4096
    cplx* T2 = tile + 4096;              // 4096
    __shared__ cplx W[64];
    int bk = blockIdx.x, tid = threadIdx.x;
    if (tid < 64) {
        float sn, cs;
        sincosf(TWO_PI * (float)tid / 64.0f, &sn, &cs);
        W[tid] = make_float2(cs, sn);
    }
    for (int t = 0; t < 16; ++t) { int e = t * 256 + tid; tile[e] = r1[bk * NPIX + e]; }
    __syncthreads();
    for (int t = 0; t < 16; ++t) {
        int e = t * 256 + tid; int z = e >> 6, xx = e & 63;
        float ax = 0.f, ay = 0.f;
        for (int o = 0; o < 64; ++o) cmac(ax, ay, tile[o * 64 + xx], W[(z * o) & 63]);
        T2[e] = make_float2(ax, ay);
    }
    __syncthreads();
    for (int t = 0; t < 16; ++t) {
        int e = t * 256 + tid; int z = e >> 6, xp = e & 63;
        float ax = 0.f;
        for (int j = 0; j < 64; ++j) {
            cplx v = T2[z * 64 + j];
            cplx w = W[(xp * j) & 63];
            ax += v.x * w.x - v.y * w.y;
        }
        x1[bk * NPIX + e] = ax * (1.0f / 4096.0f);
    }
}

// ---------------- K8: e1[b][i][p][z], e2[b][i][q][x] --------------------------
__global__ __launch_bounds__(256) void k_e(
    const float* __restrict__ p1r, const float* __restrict__ p1i,
    const float* __restrict__ p2r, const float* __restrict__ p2i,
    const float* __restrict__ t_grid, const float* __restrict__ x_grid,
    cplx* __restrict__ e1, cplx* __restrict__ e2)
{
    int idx = blockIdx.x * 256 + threadIdx.x;
    const int N1 = NC * NC * NM1 * 64;   // 65536
    const int N2 = NC * NC * NM2 * 64;   // 81920
    if (idx < N1) {
        int z = idx & 63;
        int w = idx >> 6;                // (b*16+i)*4+p
        float ty = x_grid[z];
        float pr = p1r[w] * ty, pi = p1i[w] * ty;
        float m = expf(pr);
        float sn, cs; sincosf(pi, &sn, &cs);
        e1[idx] = make_float2(m * cs, m * sn);
    } else {
        int j = idx - N1;
        if (j < N2) {
            int xx = j & 63;
            int w = j >> 6;              // (b*16+i)*5+q
            float tx = t_grid[xx];
            float pr = p2r[w] * tx, pi = p2i[w] * tx;
            float m = expf(pr);
            float sn, cs; sincosf(pi, &sn, &cs);
            e2[j] = make_float2(m * cs, m * sn);
        }
    }
}

// ---------------- K9: V[kb][i][b][q][z] = sum_p r2[kb,b,p,q]*e1[b,i,p,z] ------
__global__ __launch_bounds__(256) void k_V(
    const cplx* __restrict__ r2, const cplx* __restrict__ e1, cplx* __restrict__ V)
{
    int idx = blockIdx.x * 256 + threadIdx.x;
    const int NV = NB * NC * NC * NM2 * 64;  // 327680
    if (idx >= NV) return;
    int z = idx & 63;
    int rest = idx >> 6;
    int q = rest % 5; rest /= 5;
    int bb = rest & 15; rest >>= 4;
    int i = rest & 15;
    int kb = rest >> 4;
    float vx = 0.f, vy = 0.f;
    for (int p = 0; p < NM1; ++p)
        cmac(vx, vy, r2[((kb * 16 + bb) * NM1 + p) * NM2 + q],
                     e1[((bb * 16 + i) * NM1 + p) * 64 + z]);
    V[idx] = make_float2(vx, vy);
}

// ---------------- K10: sp = x1 + Re(V·e2)/4096; spn = instance_norm(sp) -------
__global__ __launch_bounds__(256) void k_sp(
    const cplx* __restrict__ V, const cplx* __restrict__ e2,
    const float* __restrict__ x1, float* __restrict__ spn)
{
    extern __shared__ float smem[];
    cplx* Vs = (cplx*)smem;              // 5120: [b][q][z]
    cplx* Es = Vs + 5120;                // 5120: [b][q][x]
    __shared__ float rs[256];
    int blk = blockIdx.x;                // kb*16 + i
    int i = blk & 15;
    int tid = threadIdx.x;
    for (int t = 0; t < 20; ++t) {
        int f = t * 256 + tid;
        Vs[f] = V[blk * 5120 + f];
    }
    for (int t = 0; t < 20; ++t) {
        int f = t * 256 + tid;
        int xx = f & 63; int rest = f >> 6;
        int q = rest % 5; int bb = rest / 5;
        Es[f] = e2[((bb * 16 + i) * 5 + q) * 64 + xx];
    }
    __syncthreads();
    float vals[16];
    float s = 0.f;
    for (int t = 0; t < 16; ++t) {
        int pix = t * 256 + tid;
        int z = pix >> 6, xx = pix & 63;
        float acc = 0.f;
        for (int bq = 0; bq < 80; ++bq) {
            cplx vv = Vs[bq * 64 + z];   // wave-uniform z -> broadcast
            cplx ee = Es[bq * 64 + xx];  // lane-consecutive -> conflict-free
            acc += vv.x * ee.x - vv.y * ee.y;
        }
        float v = x1[blk * NPIX + pix] + acc * (1.0f / 4096.0f);
        vals[t] = v; s += v;
    }
    rs[tid] = s; __syncthreads();
    for (int off = 128; off > 0; off >>= 1) {
        if (tid < off) rs[tid] += rs[tid + off];
        __syncthreads();
    }
    float mean = rs[0] * (1.0f / NPIX);
    __syncthreads();
    float s2 = 0.f;
    for (int t = 0; t < 16; ++t) { float d = vals[t] - mean; s2 += d * d; }
    rs[tid] = s2; __syncthreads();
    for (int off = 128; off > 0; off >>= 1) {
        if (tid < off) rs[tid] += rs[tid + off];
        __syncthreads();
    }
    float rstd = rsqrtf(rs[0] * (1.0f / NPIX) + 1e-5f);
    for (int t = 0; t < 16; ++t) {
        int pix = t * 256 + tid;
        spn[blk * NPIX + pix] = (vals[t] - mean) * rstd;
    }
}

// ---------------- K11: out = fc2( sin( fc1( spn + w0*h + w0_b ) ) ) -----------
__global__ __launch_bounds__(256) void k_final(
    const float* __restrict__ spn, const float* __restrict__ h,
    const float* __restrict__ w0_w, const float* __restrict__ w0_b,
    const float* __restrict__ fc1_w, const float* __restrict__ fc1_b,
    const float* __restrict__ fc2_w, const float* __restrict__ fc2_b,
    float* __restrict__ out)
{
    __shared__ float w1s[128 * 16], b1s[128], w2s[128], w0s[256], w0bs[16];
    int tid = threadIdx.x;
    for (int t = 0; t < 8; ++t) w1s[t * 256 + tid] = fc1_w[t * 256 + tid];
    if (tid < 128) { b1s[tid] = fc1_b[tid]; w2s[tid] = fc2_w[tid]; }
    w0s[tid] = w0_w[tid & 255];
    if (tid < 16) w0bs[tid] = w0_b[tid];
    float b2 = fc2_b[0];
    __syncthreads();
    int pix = blockIdx.x * 256 + tid;    // 0..16383
    int b = pix >> 12, rem = pix & 4095;
    float hv[16], tv[16];
    for (int c = 0; c < 16; ++c) {
        hv[c] = h[(b * 16 + c) * NPIX + rem];
        tv[c] = spn[(b * 16 + c) * NPIX + rem];
    }
    for (int k = 0; k < 16; ++k) {
        float a = w0bs[k];
        for (int c = 0; c < 16; ++c) a += w0s[k * 16 + c] * hv[c];
        tv[k] += a;
    }
    float acc = b2;
    for (int n = 0; n < 128; ++n) {
        float s1 = b1s[n];
        for (int k2 = 0; k2 < 16; ++k2) s1 += w1s[n * 16 + k2] * tv[k2];
        acc += w2s[n] * sinf(s1);
    }
    out[pix] = acc;
}

extern "C" void kernel_launch(void* const* d_in, const int* in_sizes, int n_in,
                              void* d_out, int out_size, void* d_ws, size_t ws_size,
                              hipStream_t stream)
{
    const float* x     = (const float*)d_in[0];
    const float* fc0_w = (const float*)d_in[1];
    const float* fc0_b = (const float*)d_in[2];
    const float* p1r   = (const float*)d_in[3];
    const float* p1i   = (const float*)d_in[4];
    const float* p2r   = (const float*)d_in[5];
    const float* p2i   = (const float*)d_in[6];
    const float* resr  = (const float*)d_in[7];
    const float* resi  = (const float*)d_in[8];
    const float* w0_w  = (const float*)d_in[9];
    const float* w0_b  = (const float*)d_in[10];
    const float* fc1_w = (const float*)d_in[11];
    const float* fc1_b = (const float*)d_in[12];
    const float* fc2_w = (const float*)d_in[13];
    const float* fc2_b = (const float*)d_in[14];
    const float* t_grid= (const float*)d_in[15];
    const float* x_grid= (const float*)d_in[16];
    float* out = (float*)d_out;

    float* ws = (float*)d_ws;
    size_t off = 0;
    float* h    = ws + off; off += 262144;            // (4,16,64,64)
    float* hn   = ws + off; off += 262144;
    cplx*  alpha= (cplx*)(ws + off); off += 524288;   // (4,16,64,64) c
    cplx*  A    = (cplx*)(ws + off); off += 131072;   // (64,16,16,4) c
    cplx*  Bq   = (cplx*)(ws + off); off += 163840;   // (64,16,16,5) c
    cplx*  BqT  = (cplx*)(ws + off); off += 163840;   // (16,16,5,64) c
    cplx*  G    = (cplx*)(ws + off); off += 2097152;  // (64,64,16,16) c
    cplx*  r1   = (cplx*)(ws + off); off += 524288;   // (4,16,64,64) c
    cplx*  r2   = (cplx*)(ws + off); off += 2560;     // (4,16,4,5) c
    cplx*  e1   = (cplx*)(ws + off); off += 131072;   // (16,16,4,64) c
    cplx*  e2   = (cplx*)(ws + off); off += 163840;   // (16,16,5,64) c
    cplx*  V    = (cplx*)(ws + off); off += 655360;   // (4,16,16,5,64) c
    float* x1   = ws + off; off += 262144;
    float* spn  = ws + off; off += 262144;
    (void)ws_size; (void)n_in; (void)in_sizes; (void)out_size;

    hipMemsetAsync(r2, 0, 1280 * sizeof(cplx), stream);

    k_h_inorm<<<64, 256, 0, stream>>>(x, fc0_w, fc0_b, h, hn);
    k_fft2<<<64, 256, 0, stream>>>(hn, alpha);
    k_poles<<<576, 256, 0, stream>>>(p1r, p1i, p2r, p2i, t_grid, x_grid, A, Bq, BqT);
    k_G<<<64, 256, 0, stream>>>(resr, resi, A, Bq, G);
    k_r1<<<4096, 64, 0, stream>>>(alpha, G, r1);
    k_r2<<<1024, 64, 0, stream>>>(alpha, A, BqT, resr, resi, r2);
    k_ifft2<<<64, 256, 8192 * sizeof(cplx), stream>>>(r1, x1);
    k_e<<<576, 256, 0, stream>>>(p1r, p1i, p2r, p2i, t_grid, x_grid, e1, e2);
    k_V<<<1280, 256, 0, stream>>>(r2, e1, V);
    k_sp<<<64, 256, 10240 * sizeof(cplx), stream>>>(V, e2, x1, spn);
    k_final<<<64, 256, 0, stream>>>(spn, h, w0_w, w0_b, fc1_w, fc1_b, fc2_w, fc2_b, out);
}

// Round 4
// 251.419 us; speedup vs baseline: 1.3293x; 1.3293x over previous
//
#include <hip/hip_runtime.h>

typedef float2 cplx;

constexpr int NPIX = 4096;
constexpr float TWO_PI = 6.28318530717958647692f;

__device__ inline void cmac(float& ax, float& ay, cplx a, cplx b) {
    ax += a.x * b.x - a.y * b.y;
    ay += a.x * b.y + a.y * b.x;
}

// ---- K_pre: A, Bq, Cq, e1, e2 (all independent elementwise precomputes) -----
// A [o][i][k][p]  (65536)    = 1/(i*om1[o] - p1[i,k,p])
// Bq[x][i][k][q]  (81920)    = 1/(i*om2[x] - p2[i,k,q])
// Cq[o][i][k][q]  (81920)    = sum_p res[i,k,p,q]*A[o,i,k,p]
// e1[(i*16+k)*4+p][z] (65536) = exp(p1*ty[z]);  e2[(i*16+k)*5+q][x] (81920)
__global__ __launch_bounds__(256) void k_pre(
    const float* __restrict__ p1r, const float* __restrict__ p1i,
    const float* __restrict__ p2r, const float* __restrict__ p2i,
    const float* __restrict__ resr, const float* __restrict__ resi,
    const float* __restrict__ t_grid, const float* __restrict__ x_grid,
    cplx* __restrict__ A, cplx* __restrict__ Bq, cplx* __restrict__ Cq,
    cplx* __restrict__ e1, cplx* __restrict__ e2)
{
    int idx = blockIdx.x * 256 + threadIdx.x;
    float dty = x_grid[1] - x_grid[0];
    float dtx = t_grid[1] - t_grid[0];
    const int NA = 65536, NBQ = 81920, NCQ = 81920, NE1 = 65536;
    if (idx < NA) {
        int p = idx & 3, k = (idx >> 2) & 15, i = (idx >> 6) & 15, o = idx >> 10;
        int kf = (o < 32) ? o : o - 64;
        float om = TWO_PI * (float)kf / (64.f * dty);
        float dr = -p1r[(i * 16 + k) * 4 + p], di = om - p1i[(i * 16 + k) * 4 + p];
        float inv = 1.f / (dr * dr + di * di);
        A[idx] = make_float2(dr * inv, -di * inv);
        return;
    }
    idx -= NA;
    if (idx < NBQ) {
        int q = idx % 5, k = (idx / 5) & 15, i = (idx / 80) & 15, xx = idx / 1280;
        int kf = (xx < 32) ? xx : xx - 64;
        float om = TWO_PI * (float)kf / (64.f * dtx);
        float dr = -p2r[(i * 16 + k) * 5 + q], di = om - p2i[(i * 16 + k) * 5 + q];
        float inv = 1.f / (dr * dr + di * di);
        Bq[idx] = make_float2(dr * inv, -di * inv);
        return;
    }
    idx -= NBQ;
    if (idx < NCQ) {
        int q = idx % 5, k = (idx / 5) & 15, i = (idx / 80) & 15, o = idx / 1280;
        int kf = (o < 32) ? o : o - 64;
        float om = TWO_PI * (float)kf / (64.f * dty);
        float cx = 0.f, cy = 0.f;
        for (int p = 0; p < 4; ++p) {
            float dr = -p1r[(i * 16 + k) * 4 + p], di = om - p1i[(i * 16 + k) * 4 + p];
            float inv = 1.f / (dr * dr + di * di);
            float axr = dr * inv, axi = -di * inv;
            float rr = resr[((i * 16 + k) * 4 + p) * 5 + q];
            float ri = resi[((i * 16 + k) * 4 + p) * 5 + q];
            cx += rr * axr - ri * axi;
            cy += rr * axi + ri * axr;
        }
        Cq[idx] = make_float2(cx, cy);
        return;
    }
    idx -= NCQ;
    if (idx < NE1) {
        int z = idx & 63, w = idx >> 6;
        float t = x_grid[z];
        float m = expf(p1r[w] * t);
        float sn, cs; sincosf(p1i[w] * t, &sn, &cs);
        e1[idx] = make_float2(m * cs, m * sn);
        return;
    }
    idx -= NE1;
    {   // e2
        int xx = idx & 63, w = idx >> 6;
        float t = t_grid[xx];
        float m = expf(p2r[w] * t);
        float sn, cs; sincosf(p2i[w] * t, &sn, &cs);
        e2[idx] = make_float2(m * cs, m * sn);
    }
}

// ---- K1: h = fc0(x,gx,gy); hn = inorm(h) (LDS only); T1 = fft-stage-A(hn) ---
__global__ __launch_bounds__(1024) void k1_h_norm_fftA(
    const float* __restrict__ x, const float* __restrict__ fc0_w,
    const float* __restrict__ fc0_b, float* __restrict__ h, cplx* __restrict__ T1)
{
    __shared__ float tile[4096];
    __shared__ float rs[32];
    __shared__ cplx Ws[64];
    int bc = blockIdx.x, b = bc >> 4, c = bc & 15;
    int tid = threadIdx.x;
    if (tid < 64) { float sn, cs; sincosf(-TWO_PI * tid / 64.f, &sn, &cs); Ws[tid] = make_float2(cs, sn); }
    float w0 = fc0_w[c * 3], w1 = fc0_w[c * 3 + 1], w2 = fc0_w[c * 3 + 2], bb = fc0_b[c];
    const float inv63 = 1.f / 63.f;
    float vals[4]; float s = 0.f;
    for (int t = 0; t < 4; ++t) {
        int pix = t * 1024 + tid; int z = pix >> 6, xx = pix & 63;
        float v = w0 * x[b * 4096 + pix] + w1 * (z * inv63) + w2 * (xx * inv63) + bb;
        vals[t] = v; s += v; h[bc * 4096 + pix] = v;
    }
    for (int m = 32; m; m >>= 1) s += __shfl_xor(s, m, 64);
    if ((tid & 63) == 0) rs[tid >> 6] = s;
    __syncthreads();
    if (tid == 0) { float t0 = 0; for (int w = 0; w < 16; ++w) t0 += rs[w]; rs[16] = t0; }
    __syncthreads();
    float mean = rs[16] * (1.f / 4096.f);
    float s2 = 0.f;
    for (int t = 0; t < 4; ++t) { float d = vals[t] - mean; s2 += d * d; }
    for (int m = 32; m; m >>= 1) s2 += __shfl_xor(s2, m, 64);
    __syncthreads();
    if ((tid & 63) == 0) rs[tid >> 6] = s2;
    __syncthreads();
    if (tid == 0) { float t0 = 0; for (int w = 0; w < 16; ++w) t0 += rs[w]; rs[16] = t0; }
    __syncthreads();
    float rstd = rsqrtf(rs[16] * (1.f / 4096.f) + 1e-5f);
    for (int t = 0; t < 4; ++t) { int pix = t * 1024 + tid; tile[pix] = (vals[t] - mean) * rstd; }
    __syncthreads();
    // stage A: T1[p][j] = sum_i tile[i][j] * W^(p*i)
    int j = tid & 63, pl = tid >> 6;
    for (int t = 0; t < 4; ++t) {
        int p = pl + t * 16;
        float ax = 0.f, ay = 0.f;
        #pragma unroll 8
        for (int i = 0; i < 64; ++i) {
            float v = tile[i * 64 + j];
            cplx w = Ws[(p * i) & 63];
            ax += v * w.x; ay += v * w.y;
        }
        T1[bc * 4096 + p * 64 + j] = make_float2(ax, ay);
    }
}

// ---- K2: fft-stage-B: alpha[p][q] = sum_j T1[p][j]*W^(q*j); also alphaT -----
__global__ __launch_bounds__(256) void k2_fftB(
    const cplx* __restrict__ T1, cplx* __restrict__ alpha, cplx* __restrict__ alphaT)
{
    __shared__ cplx T1s[256];
    __shared__ cplx Ws[64];
    int bc = blockIdx.x >> 4, pc = blockIdx.x & 15;
    int tid = threadIdx.x;
    if (tid < 64) { float sn, cs; sincosf(-TWO_PI * tid / 64.f, &sn, &cs); Ws[tid] = make_float2(cs, sn); }
    T1s[tid] = T1[bc * 4096 + pc * 256 + tid];
    __syncthreads();
    int q = tid & 63, pl = tid >> 6, p = pc * 4 + pl;
    float ax = 0.f, ay = 0.f;
    #pragma unroll 8
    for (int j = 0; j < 64; ++j) cmac(ax, ay, T1s[pl * 64 + j], Ws[(q * j) & 63]);
    cplx v = make_float2(ax, ay);
    alpha [bc * 4096 + p * 64 + q] = v;
    alphaT[(p * 64 + q) * 64 + bc] = v;
}

// ---- K3: fused G+r1 per (o,x): G[i][k]=sum_q Cq*Bq; r1[b,k]=sum_i a[b,i]*G --
__global__ __launch_bounds__(64) void k3_r1(
    const cplx* __restrict__ alphaT, const cplx* __restrict__ Cq,
    const cplx* __restrict__ Bq, cplx* __restrict__ r1)
{
    __shared__ cplx Cqs[1280], Bqs[1280], Gs[256], as[64];
    int ox = blockIdx.x; int o = ox >> 6, xx = ox & 63;
    int t = threadIdx.x;
    for (int m = 0; m < 20; ++m) {
        Cqs[m * 64 + t] = Cq[o * 1280 + m * 64 + t];
        Bqs[m * 64 + t] = Bq[xx * 1280 + m * 64 + t];
    }
    as[t] = alphaT[ox * 64 + t];
    __syncthreads();
    for (int m = 0; m < 4; ++m) {
        int e = m * 64 + t; int i = e >> 4, k = e & 15;
        float gx = 0.f, gy = 0.f;
        for (int q = 0; q < 5; ++q) cmac(gx, gy, Cqs[i * 80 + k * 5 + q], Bqs[i * 80 + k * 5 + q]);
        Gs[e] = make_float2(gx, gy);
    }
    __syncthreads();
    int b = t >> 4, k = t & 15;
    float ax = 0.f, ay = 0.f;
    for (int i = 0; i < 16; ++i) cmac(ax, ay, as[b * 16 + i], Gs[i * 16 + k]);
    r1[t * 4096 + ox] = make_float2(ax, ay);
}

// ---- K4: inner1[bi][o][k][q] = sum_x alpha[bi][o][x] * Bq[x][i][k][q] -------
__global__ __launch_bounds__(256) void k4_inner1(
    const cplx* __restrict__ alpha, const cplx* __restrict__ Bq,
    cplx* __restrict__ inner1)
{
    int idx = blockIdx.x * 256 + threadIdx.x;      // bi*5120 + o*80 + kq
    int kq = idx % 80; int r = idx / 80; int o = r & 63; int bi = r >> 6; int i = bi & 15;
    const cplx* arow = alpha + bi * 4096 + o * 64;
    const cplx* bcol = Bq + i * 80 + kq;
    float ax = 0.f, ay = 0.f;
    #pragma unroll 4
    for (int x = 0; x < 64; ++x) cmac(ax, ay, arow[x], bcol[x * 1280]);
    inner1[idx] = make_float2(ax, ay);
}

// ---- K5: r2[b][k][p][q] = sum_i res[i,k,p,q] * sum_o A[o,i,k,p]*inner1 ------
__global__ __launch_bounds__(64) void k5_r2(
    const cplx* __restrict__ A, const cplx* __restrict__ inner1,
    const float* __restrict__ resr, const float* __restrict__ resi,
    cplx* __restrict__ r2)
{
    int bk = blockIdx.x; int b = bk >> 4, k = bk & 15;
    int o = threadIdx.x;
    float accx[4][5] = {}, accy[4][5] = {};
    for (int i = 0; i < 16; ++i) {
        cplx a[4];
        for (int p = 0; p < 4; ++p) a[p] = A[((o * 16 + i) * 16 + k) * 4 + p];
        cplx in[5];
        for (int q = 0; q < 5; ++q) in[q] = inner1[(b * 16 + i) * 5120 + o * 80 + k * 5 + q];
        int rb = (i * 16 + k) * 20;
        for (int p = 0; p < 4; ++p)
            for (int q = 0; q < 5; ++q) {
                float tx = a[p].x * in[q].x - a[p].y * in[q].y;
                float ty = a[p].x * in[q].y + a[p].y * in[q].x;
                float rr = resr[rb + p * 5 + q], ri = resi[rb + p * 5 + q];
                accx[p][q] += rr * tx - ri * ty;
                accy[p][q] += rr * ty + ri * tx;
            }
    }
    for (int m = 32; m; m >>= 1)
        for (int p = 0; p < 4; ++p)
            for (int q = 0; q < 5; ++q) {
                accx[p][q] += __shfl_xor(accx[p][q], m, 64);
                accy[p][q] += __shfl_xor(accy[p][q], m, 64);
            }
    if (o == 0)
        for (int p = 0; p < 4; ++p)
            for (int q = 0; q < 5; ++q)
                r2[bk * 20 + p * 5 + q] = make_float2(accx[p][q], accy[p][q]);
}

// ---- K6: V[kb][i][bb][q][z] = sum_p r2[kb,bb,p,q]*e1[bb,i,p,z] --------------
__global__ __launch_bounds__(256) void k6_V(
    const cplx* __restrict__ r2, const cplx* __restrict__ e1, cplx* __restrict__ V)
{
    int idx = blockIdx.x * 256 + threadIdx.x;
    int z = idx & 63;
    int rest = idx >> 6;
    int q = rest % 5; rest /= 5;
    int bb = rest & 15; rest >>= 4;
    int i = rest & 15;
    int kb = rest >> 4;
    float vx = 0.f, vy = 0.f;
    for (int p = 0; p < 4; ++p)
        cmac(vx, vy, r2[((kb * 16 + bb) * 4 + p) * 5 + q],
                     e1[((bb * 16 + i) * 4 + p) * 64 + z]);
    V[idx] = make_float2(vx, vy);
}

// ---- K7: ifft-stage-A: T2[z][j] = sum_o r1[o][j]*Wp^(z*o) -------------------
__global__ __launch_bounds__(256) void k7_ifftA(
    const cplx* __restrict__ r1, cplx* __restrict__ T2)
{
    __shared__ cplx Ws[64];
    int bk = blockIdx.x >> 4, zc = blockIdx.x & 15;
    int tid = threadIdx.x;
    if (tid < 64) { float sn, cs; sincosf(TWO_PI * tid / 64.f, &sn, &cs); Ws[tid] = make_float2(cs, sn); }
    __syncthreads();
    int j = tid & 63, z = zc * 4 + (tid >> 6);
    const cplx* rr = r1 + bk * 4096 + j;
    float ax = 0.f, ay = 0.f;
    #pragma unroll 4
    for (int o = 0; o < 64; ++o) cmac(ax, ay, rr[o * 64], Ws[(z * o) & 63]);
    T2[bk * 4096 + z * 64 + j] = make_float2(ax, ay);
}

// ---- K8: sp = ifft-stage-B(T2) + Re(V*e2); spn = inorm(sp) ------------------
__global__ __launch_bounds__(1024) void k8_sp(
    const cplx* __restrict__ T2, const cplx* __restrict__ V,
    const cplx* __restrict__ e2, float* __restrict__ spn)
{
    __shared__ cplx Es[5120];
    __shared__ float rs[32];
    __shared__ cplx Ws[64];
    int blk = blockIdx.x;           // b*16+ch
    int ch = blk & 15;
    int tid = threadIdx.x;
    if (tid < 64) { float sn, cs; sincosf(TWO_PI * tid / 64.f, &sn, &cs); Ws[tid] = make_float2(cs, sn); }
    for (int t = 0; t < 5; ++t) {
        int f = t * 1024 + tid; int xx = f & 63, bq = f >> 6; int bb = bq / 5, q = bq % 5;
        Es[f] = e2[((bb * 16 + ch) * 5 + q) * 64 + xx];
    }
    __syncthreads();
    const cplx* T2b = T2 + blk * 4096;
    const cplx* Vb  = V  + blk * 5120;
    int xx = tid & 63;
    float vals[4]; float s = 0.f;
    for (int t = 0; t < 4; ++t) {
        int pix = t * 1024 + tid; int z = pix >> 6;
        float acc = 0.f;
        const cplx* trow = T2b + z * 64;
        #pragma unroll 4
        for (int j2 = 0; j2 < 64; ++j2) {
            cplx v = trow[j2]; cplx w = Ws[(xx * j2) & 63];
            acc += v.x * w.x - v.y * w.y;
        }
        #pragma unroll 4
        for (int bq = 0; bq < 80; ++bq) {
            cplx vv = Vb[bq * 64 + z];   // wave-uniform z -> broadcast
            cplx ee = Es[bq * 64 + xx];  // lane-consecutive
            acc += vv.x * ee.x - vv.y * ee.y;
        }
        float val = acc * (1.f / 4096.f);
        vals[t] = val; s += val;
    }
    for (int m = 32; m; m >>= 1) s += __shfl_xor(s, m, 64);
    if ((tid & 63) == 0) rs[tid >> 6] = s;
    __syncthreads();
    if (tid == 0) { float t0 = 0; for (int w = 0; w < 16; ++w) t0 += rs[w]; rs[16] = t0; }
    __syncthreads();
    float mean = rs[16] * (1.f / 4096.f);
    float s2 = 0.f;
    for (int t = 0; t < 4; ++t) { float d = vals[t] - mean; s2 += d * d; }
    for (int m = 32; m; m >>= 1) s2 += __shfl_xor(s2, m, 64);
    __syncthreads();
    if ((tid & 63) == 0) rs[tid >> 6] = s2;
    __syncthreads();
    if (tid == 0) { float t0 = 0; for (int w = 0; w < 16; ++w) t0 += rs[w]; rs[16] = t0; }
    __syncthreads();
    float rstd = rsqrtf(rs[16] * (1.f / 4096.f) + 1e-5f);
    for (int t = 0; t < 4; ++t) {
        int pix = t * 1024 + tid;
        spn[blk * 4096 + pix] = (vals[t] - mean) * rstd;
    }
}

// ---- K9: out = fc2( sin( fc1( spn + w0*h + w0_b ) ) ) -----------------------
__global__ __launch_bounds__(256) void k9_final(
    const float* __restrict__ spn, const float* __restrict__ h,
    const float* __restrict__ w0_w, const float* __restrict__ w0_b,
    const float* __restrict__ fc1_w, const float* __restrict__ fc1_b,
    const float* __restrict__ fc2_w, const float* __restrict__ fc2_b,
    float* __restrict__ out)
{
    __shared__ float w1s[128 * 16], b1s[128], w2s[128], w0s[256], w0bs[16];
    int tid = threadIdx.x;
    for (int t = 0; t < 8; ++t) w1s[t * 256 + tid] = fc1_w[t * 256 + tid];
    if (tid < 128) { b1s[tid] = fc1_b[tid]; w2s[tid] = fc2_w[tid]; }
    w0s[tid] = w0_w[tid & 255];
    if (tid < 16) w0bs[tid] = w0_b[tid];
    float b2 = fc2_b[0];
    __syncthreads();
    int pix = blockIdx.x * 256 + tid;    // 0..16383
    int b = pix >> 12, rem = pix & 4095;
    float hv[16], tv[16];
    for (int c = 0; c < 16; ++c) {
        hv[c] = h[(b * 16 + c) * 4096 + rem];
        tv[c] = spn[(b * 16 + c) * 4096 + rem];
    }
    for (int k = 0; k < 16; ++k) {
        float a = w0bs[k];
        for (int c = 0; c < 16; ++c) a += w0s[k * 16 + c] * hv[c];
        tv[k] += a;
    }
    float acc = b2;
    for (int n = 0; n < 128; ++n) {
        float s1 = b1s[n];
        for (int k2 = 0; k2 < 16; ++k2) s1 += w1s[n * 16 + k2] * tv[k2];
        acc += w2s[n] * sinf(s1);
    }
    out[pix] = acc;
}

extern "C" void kernel_launch(void* const* d_in, const int* in_sizes, int n_in,
                              void* d_out, int out_size, void* d_ws, size_t ws_size,
                              hipStream_t stream)
{
    const float* x     = (const float*)d_in[0];
    const float* fc0_w = (const float*)d_in[1];
    const float* fc0_b = (const float*)d_in[2];
    const float* p1r   = (const float*)d_in[3];
    const float* p1i   = (const float*)d_in[4];
    const float* p2r   = (const float*)d_in[5];
    const float* p2i   = (const float*)d_in[6];
    const float* resr  = (const float*)d_in[7];
    const float* resi  = (const float*)d_in[8];
    const float* w0_w  = (const float*)d_in[9];
    const float* w0_b  = (const float*)d_in[10];
    const float* fc1_w = (const float*)d_in[11];
    const float* fc1_b = (const float*)d_in[12];
    const float* fc2_w = (const float*)d_in[13];
    const float* fc2_b = (const float*)d_in[14];
    const float* t_grid= (const float*)d_in[15];
    const float* x_grid= (const float*)d_in[16];
    float* out = (float*)d_out;

    float* ws = (float*)d_ws;
    size_t off = 0;
    float* h      = ws + off; off += 262144;            // (64,4096)
    cplx*  T1     = (cplx*)(ws + off); off += 524288;   // (64,4096) c
    cplx*  alpha  = (cplx*)(ws + off); off += 524288;   // [bi][o][x] c
    cplx*  alphaT = (cplx*)(ws + off); off += 524288;   // [ox][bi] c
    cplx*  A      = (cplx*)(ws + off); off += 131072;   // (64,16,16,4) c
    cplx*  Bq     = (cplx*)(ws + off); off += 163840;   // (64,16,16,5) c
    cplx*  Cq     = (cplx*)(ws + off); off += 163840;   // (64,16,16,5) c
    cplx*  e1     = (cplx*)(ws + off); off += 131072;   // (16,16,4,64) c
    cplx*  e2     = (cplx*)(ws + off); off += 163840;   // (16,16,5,64) c
    cplx*  r1     = (cplx*)(ws + off); off += 524288;   // [bk][o][x] c
    cplx*  inner1 = (cplx*)(ws + off); off += 655360;   // [bi][o][k][q] c
    cplx*  r2     = (cplx*)(ws + off); off += 2560;     // (4,16,4,5) c
    cplx*  V      = (cplx*)(ws + off); off += 655360;   // (4,16,16,5,64) c
    cplx*  T2     = (cplx*)(ws + off); off += 524288;   // [bk][z][j] c
    float* spn    = ws + off; off += 262144;
    (void)ws_size; (void)n_in; (void)in_sizes; (void)out_size;

    k_pre<<<1472, 256, 0, stream>>>(p1r, p1i, p2r, p2i, resr, resi, t_grid, x_grid,
                                    A, Bq, Cq, e1, e2);
    k1_h_norm_fftA<<<64, 1024, 0, stream>>>(x, fc0_w, fc0_b, h, T1);
    k2_fftB<<<1024, 256, 0, stream>>>(T1, alpha, alphaT);
    k3_r1<<<4096, 64, 0, stream>>>(alphaT, Cq, Bq, r1);
    k4_inner1<<<1280, 256, 0, stream>>>(alpha, Bq, inner1);
    k5_r2<<<64, 64, 0, stream>>>(A, inner1, resr, resi, r2);
    k6_V<<<1280, 256, 0, stream>>>(r2, e1, V);
    k7_ifftA<<<1024, 256, 0, stream>>>(r1, T2);
    k8_sp<<<64, 1024, 0, stream>>>(T2, V, e2, spn);
    k9_final<<<64, 256, 0, stream>>>(spn, h, w0_w, w0_b, fc1_w, fc1_b, fc2_w, fc2_b, out);
}